// Round 1
// 603.161 us; speedup vs baseline: 1.0436x; 1.0436x over previous
//
#include <hip/hip_runtime.h>
#include <hip/hip_bf16.h>

#define M_NODES 100000
#define N_EDGES 1600000
#define K_IN 512
#define N_OUT 256

typedef short bf16x8 __attribute__((ext_vector_type(8)));
typedef float f32x4 __attribute__((ext_vector_type(4)));

#define GLOBAL_AS __attribute__((address_space(1)))
#define LDS_AS __attribute__((address_space(3)))

__device__ inline unsigned short f2bf_u(float f) {
  union { float f; unsigned u; } x; x.f = f;
  unsigned r = x.u + 0x7FFFu + ((x.u >> 16) & 1u);
  return (unsigned short)(r >> 16);
}
__device__ inline float bfu2f(unsigned short h) {
  union { unsigned u; float f; } x; x.u = ((unsigned)h) << 16;
  return x.f;
}

// weight [512][256] f32 -> Wt bf16 [256][512] (transposed: B-frag k-contiguous)
__global__ void prep_w_kernel(const float* __restrict__ w, short* __restrict__ wt) {
  int idx = blockIdx.x * 256 + threadIdx.x;   // 131072 total
  int k = idx >> 8, n = idx & 255;
  wt[n * K_IN + k] = (short)f2bf_u(w[idx]);
}

// row_ptr[r] = lower_bound(row, r) over sorted row[] (COO -> CSR)
__global__ void build_rp_kernel(const int* __restrict__ row, int* __restrict__ rp) {
  int r = blockIdx.x * 256 + threadIdx.x;
  if (r > M_NODES) return;
  int lo = 0, hi = N_EDGES;
  while (lo < hi) {
    int mid = (lo + hi) >> 1;
    if (row[mid] < r) lo = mid + 1; else hi = mid;
  }
  rp[r] = lo;
}

// H = bf16(tanh(A @ W)). A fp32 [M,512], Wt bf16 [256][512].
// Block: 256 thr, M_TILE=64, N=256, BK=64. LDS XOR-swizzled in 16B chunks:
// element [r][k] lives at r*ROWB + ((k/8) ^ (r&7))*8 shorts.
__global__ __launch_bounds__(256) void gemm_tanh_kernel(
    const float* __restrict__ A, const short* __restrict__ Wt,
    unsigned short* __restrict__ H) {
  __shared__ __align__(16) short As[64 * 64];    // 8KB  (rows 0..63, 64 k)
  __shared__ __align__(16) short Bs[256 * 64];   // 32KB (n 0..255, 64 k)
  const int tid = threadIdx.x;
  const int wave = tid >> 6, lane = tid & 63;
  const int quad = lane >> 4, l16 = lane & 15;
  const int row0 = blockIdx.x * 64;

  f32x4 acc[16];
  #pragma unroll
  for (int i = 0; i < 16; ++i) acc[i] = (f32x4){0.f, 0.f, 0.f, 0.f};

  const int ra = tid >> 2;             // 0..63 : A tile row
  const int kb = (tid & 3) << 4;       // 0,16,32,48 : k offset (floats)
  const int gr = min(row0 + ra, M_NODES - 1);
  const float* Arow = A + (size_t)gr * K_IN;

  for (int k0 = 0; k0 < K_IN; k0 += 64) {
    // --- B: async global->LDS, swizzled. wave covers n in [64*wave, 64*wave+64)
    #pragma unroll
    for (int it = 0; it < 8; ++it) {
      int g = wave * 512 + it * 64 + lane;     // chunk id in Bs
      int n = g >> 3, phys = g & 7;
      int j = phys ^ (n & 7);                  // logical k-chunk
      const short* gp = Wt + (size_t)n * K_IN + k0 + j * 8;
      __builtin_amdgcn_global_load_lds(
          (GLOBAL_AS const void*)gp,
          (LDS_AS void*)&Bs[(wave * 512 + it * 64) * 8],
          16, 0, 0);
    }
    // --- A: 4 float4 -> 16 bf16 -> 2 swizzled chunk writes
    float4 a0 = *(const float4*)&Arow[k0 + kb];
    float4 a1 = *(const float4*)&Arow[k0 + kb + 4];
    float4 a2 = *(const float4*)&Arow[k0 + kb + 8];
    float4 a3 = *(const float4*)&Arow[k0 + kb + 12];
    union { unsigned short s[16]; int4 v[2]; } u;
    u.s[0]=f2bf_u(a0.x); u.s[1]=f2bf_u(a0.y); u.s[2]=f2bf_u(a0.z); u.s[3]=f2bf_u(a0.w);
    u.s[4]=f2bf_u(a1.x); u.s[5]=f2bf_u(a1.y); u.s[6]=f2bf_u(a1.z); u.s[7]=f2bf_u(a1.w);
    u.s[8]=f2bf_u(a2.x); u.s[9]=f2bf_u(a2.y); u.s[10]=f2bf_u(a2.z); u.s[11]=f2bf_u(a2.w);
    u.s[12]=f2bf_u(a3.x); u.s[13]=f2bf_u(a3.y); u.s[14]=f2bf_u(a3.z); u.s[15]=f2bf_u(a3.w);
    int lc0 = kb >> 3;                         // logical chunk of first 8 bf16
    #pragma unroll
    for (int c = 0; c < 2; ++c) {
      int phys = (lc0 + c) ^ (ra & 7);
      *(int4*)&As[ra * 64 + phys * 8] = u.v[c];
    }
    __syncthreads();
    // --- MFMA: A-frag m=l16,k=quad*8+j ; B-frag n=l16,k=quad*8+j ; swizzled reads
    const int r = wave * 16 + l16;
    #pragma unroll
    for (int kstep = 0; kstep < 2; ++kstep) {
      int lc = kstep * 4 + quad;
      bf16x8 af = *(const bf16x8*)&As[r * 64 + (lc ^ (r & 7)) * 8];
      #pragma unroll
      for (int nt = 0; nt < 16; ++nt) {
        int n = nt * 16 + l16;
        bf16x8 bfr = *(const bf16x8*)&Bs[n * 64 + (lc ^ (n & 7)) * 8];
        acc[nt] = __builtin_amdgcn_mfma_f32_16x16x32_bf16(af, bfr, acc[nt], 0, 0, 0);
      }
    }
    __syncthreads();
  }
  // epilogue: C/D row=quad*4+reg, col=l16 ; store bf16
  #pragma unroll
  for (int nt = 0; nt < 16; ++nt) {
    #pragma unroll
    for (int rr = 0; rr < 4; ++rr) {
      int row = row0 + wave * 16 + quad * 4 + rr;
      if (row < M_NODES) {
        H[(size_t)row * N_OUT + nt * 16 + l16] = f2bf_u(tanhf(acc[nt][rr]));
      }
    }
  }
}

// y[i,:] = sum_e vals[e]*x[col[e],:], x bf16 [M,256]. One wave/row; lane holds
// 4 features (8B/edge/lane -> full 512B row per edge, coalesced).
// Edge metadata (col/vals) is loaded ONCE per 64-edge chunk as a per-lane
// vector load, then broadcast via __shfl -> the x-row gathers have no
// load->load dependency and are issued 8-deep (MLP=8 per wave).
__global__ __launch_bounds__(256) void spmm_bf_bf(
    const int* __restrict__ rp, const int* __restrict__ colv,
    const float* __restrict__ vals, const unsigned short* __restrict__ x,
    unsigned short* __restrict__ y) {
  int w = (blockIdx.x * 256 + threadIdx.x) >> 6;
  int lane = threadIdx.x & 63;
  int i = __builtin_amdgcn_readfirstlane(w);
  int s = rp[i], e = rp[i + 1];
  float a0 = 0.f, a1 = 0.f, a2 = 0.f, a3 = 0.f;
  const unsigned short* xl = x + lane * 4;
  for (int base = s; base < e; base += 64) {
    int nn = min(e - base, 64);
    int tl = min(base + lane, e - 1);          // clamped: lanes >= nn unused
    int c_l = colv[tl];
    float v_l = vals[tl];
    int tt = 0;
    for (; tt + 8 <= nn; tt += 8) {
      ushort4 xv[8]; float vv[8];
      #pragma unroll
      for (int j = 0; j < 8; ++j) {
        int c = __shfl(c_l, tt + j);
        vv[j] = __shfl(v_l, tt + j);
        xv[j] = *(const ushort4*)(xl + (size_t)c * N_OUT);
      }
      #pragma unroll
      for (int j = 0; j < 8; ++j) {
        a0 += vv[j] * bfu2f(xv[j].x); a1 += vv[j] * bfu2f(xv[j].y);
        a2 += vv[j] * bfu2f(xv[j].z); a3 += vv[j] * bfu2f(xv[j].w);
      }
    }
    for (; tt + 4 <= nn; tt += 4) {
      ushort4 xv[4]; float vv[4];
      #pragma unroll
      for (int j = 0; j < 4; ++j) {
        int c = __shfl(c_l, tt + j);
        vv[j] = __shfl(v_l, tt + j);
        xv[j] = *(const ushort4*)(xl + (size_t)c * N_OUT);
      }
      #pragma unroll
      for (int j = 0; j < 4; ++j) {
        a0 += vv[j] * bfu2f(xv[j].x); a1 += vv[j] * bfu2f(xv[j].y);
        a2 += vv[j] * bfu2f(xv[j].z); a3 += vv[j] * bfu2f(xv[j].w);
      }
    }
    for (; tt < nn; ++tt) {
      int c = __shfl(c_l, tt);
      float v = __shfl(v_l, tt);
      ushort4 xv = *(const ushort4*)(xl + (size_t)c * N_OUT);
      a0 += v * bfu2f(xv.x); a1 += v * bfu2f(xv.y);
      a2 += v * bfu2f(xv.z); a3 += v * bfu2f(xv.w);
    }
  }
  ushort4 o;
  o.x = f2bf_u(a0); o.y = f2bf_u(a1); o.z = f2bf_u(a2); o.w = f2bf_u(a3);
  *(ushort4*)(y + (size_t)i * N_OUT + lane * 4) = o;
}

// same but f32 output (final layer writes d_out)
__global__ __launch_bounds__(256) void spmm_bf_f32(
    const int* __restrict__ rp, const int* __restrict__ colv,
    const float* __restrict__ vals, const unsigned short* __restrict__ x,
    float* __restrict__ y) {
  int w = (blockIdx.x * 256 + threadIdx.x) >> 6;
  int lane = threadIdx.x & 63;
  int i = __builtin_amdgcn_readfirstlane(w);
  int s = rp[i], e = rp[i + 1];
  float a0 = 0.f, a1 = 0.f, a2 = 0.f, a3 = 0.f;
  const unsigned short* xl = x + lane * 4;
  for (int base = s; base < e; base += 64) {
    int nn = min(e - base, 64);
    int tl = min(base + lane, e - 1);
    int c_l = colv[tl];
    float v_l = vals[tl];
    int tt = 0;
    for (; tt + 8 <= nn; tt += 8) {
      ushort4 xv[8]; float vv[8];
      #pragma unroll
      for (int j = 0; j < 8; ++j) {
        int c = __shfl(c_l, tt + j);
        vv[j] = __shfl(v_l, tt + j);
        xv[j] = *(const ushort4*)(xl + (size_t)c * N_OUT);
      }
      #pragma unroll
      for (int j = 0; j < 8; ++j) {
        a0 += vv[j] * bfu2f(xv[j].x); a1 += vv[j] * bfu2f(xv[j].y);
        a2 += vv[j] * bfu2f(xv[j].z); a3 += vv[j] * bfu2f(xv[j].w);
      }
    }
    for (; tt + 4 <= nn; tt += 4) {
      ushort4 xv[4]; float vv[4];
      #pragma unroll
      for (int j = 0; j < 4; ++j) {
        int c = __shfl(c_l, tt + j);
        vv[j] = __shfl(v_l, tt + j);
        xv[j] = *(const ushort4*)(xl + (size_t)c * N_OUT);
      }
      #pragma unroll
      for (int j = 0; j < 4; ++j) {
        a0 += vv[j] * bfu2f(xv[j].x); a1 += vv[j] * bfu2f(xv[j].y);
        a2 += vv[j] * bfu2f(xv[j].z); a3 += vv[j] * bfu2f(xv[j].w);
      }
    }
    for (; tt < nn; ++tt) {
      int c = __shfl(c_l, tt);
      float v = __shfl(v_l, tt);
      ushort4 xv = *(const ushort4*)(xl + (size_t)c * N_OUT);
      a0 += v * bfu2f(xv.x); a1 += v * bfu2f(xv.y);
      a2 += v * bfu2f(xv.z); a3 += v * bfu2f(xv.w);
    }
  }
  float4 o = {a0, a1, a2, a3};
  *(float4*)(y + (size_t)i * N_OUT + lane * 4) = o;
}

extern "C" void kernel_launch(void* const* d_in, const int* in_sizes, int n_in,
                              void* d_out, int out_size, void* d_ws, size_t ws_size,
                              hipStream_t stream) {
  const float* features = (const float*)d_in[0];
  const float* weight   = (const float*)d_in[1];
  const int*   row      = (const int*)d_in[2];
  const int*   col      = (const int*)d_in[3];
  const float* vals     = (const float*)d_in[4];
  float* out = (float*)d_out;

  char* ws = (char*)d_ws;
  const size_t HB = (size_t)M_NODES * N_OUT * 2;   // 51,200,000 bf16 H
  const size_t RPB = 400016;                        // 100001 ints padded
  unsigned short* H  = (unsigned short*)ws;
  unsigned short* y1 = (unsigned short*)(ws + HB);
  int*   rp = (int*)(ws + 2 * HB);
  short* Wt = (short*)(ws + 2 * HB + RPB);
  // total need: 2*51.2MB + 400016 + 262144 = 103,062,160 B (== round-1 min, fits)

  prep_w_kernel<<<512, 256, 0, stream>>>(weight, Wt);
  build_rp_kernel<<<(M_NODES + 1 + 255) / 256, 256, 0, stream>>>(row, rp);
  gemm_tanh_kernel<<<(M_NODES + 63) / 64, 256, 0, stream>>>(features, Wt, H);
  spmm_bf_bf<<<25000, 256, 0, stream>>>(rp, col, vals, H, y1);
  spmm_bf_f32<<<25000, 256, 0, stream>>>(rp, col, vals, y1, out);
}

// Round 2
// 598.898 us; speedup vs baseline: 1.0511x; 1.0071x over previous
//
#include <hip/hip_runtime.h>
#include <hip/hip_bf16.h>

#define M_NODES 100000
#define N_EDGES 1600000
#define K_IN 512
#define N_OUT 256

typedef short bf16x8 __attribute__((ext_vector_type(8)));
typedef float f32x4 __attribute__((ext_vector_type(4)));

#define GLOBAL_AS __attribute__((address_space(1)))
#define LDS_AS __attribute__((address_space(3)))

__device__ inline unsigned short f2bf_u(float f) {
  union { float f; unsigned u; } x; x.f = f;
  unsigned r = x.u + 0x7FFFu + ((x.u >> 16) & 1u);
  return (unsigned short)(r >> 16);
}
__device__ inline float bfu2f(unsigned short h) {
  union { unsigned u; float f; } x; x.u = ((unsigned)h) << 16;
  return x.f;
}
// tanh(x) = sign(x) * (1-z)/(1+z), z = exp(-2|x|). ~7 VALU + 1 trans.
__device__ inline float fast_tanh(float x) {
  float ax = __builtin_fabsf(x);
  float z = __expf(-2.0f * ax);
  float t = (1.0f - z) * __builtin_amdgcn_rcpf(1.0f + z);
  return __builtin_copysignf(t, x);
}

// weight [512][256] f32 -> Wt bf16 [256][512] (transposed: B-frag k-contiguous)
__global__ void prep_w_kernel(const float* __restrict__ w, short* __restrict__ wt) {
  int idx = blockIdx.x * 256 + threadIdx.x;   // 131072 total
  int k = idx >> 8, n = idx & 255;
  wt[n * K_IN + k] = (short)f2bf_u(w[idx]);
}

// row_ptr[r] = lower_bound(row, r) over sorted row[] (COO -> CSR)
__global__ void build_rp_kernel(const int* __restrict__ row, int* __restrict__ rp) {
  int r = blockIdx.x * 256 + threadIdx.x;
  if (r > M_NODES) return;
  int lo = 0, hi = N_EDGES;
  while (lo < hi) {
    int mid = (lo + hi) >> 1;
    if (row[mid] < r) lo = mid + 1; else hi = mid;
  }
  rp[r] = lo;
}

// H = bf16(tanh(A @ W)). A fp32 [M,512], Wt bf16 [256][512] (L2-resident).
// Block: 256 thr = 4 waves, tile M=64 x N=256. Wave w owns n in [64w,64w+64)
// (64x64 register tile, acc[4][4] f32x4). B-fragments load STRAIGHT FROM
// GLOBAL (Wt is 256KB, L2-resident; staging via LDS would move the same
// bytes through L2 anyway). Only A goes through LDS: double-buffered 8KB
// bf16 tiles, XOR-swizzled 16B chunks (elem [r][k] at chunk (k/8)^(r&7)),
// ONE barrier per 64-k step. Next A chunk is prefetched into registers
// during compute, converted+written to the other buffer before the barrier.
__global__ __launch_bounds__(256, 4) void gemm_tanh_kernel(
    const float* __restrict__ A, const short* __restrict__ Wt,
    unsigned short* __restrict__ H) {
  __shared__ __align__(16) short As[2][64 * 64];   // 2 x 8KB
  const int tid = threadIdx.x;
  const int wave = tid >> 6, lane = tid & 63;
  const int quad = lane >> 4, l16 = lane & 15;
  const int row0 = blockIdx.x * 64;

  f32x4 acc[4][4];   // [m][nt]
  #pragma unroll
  for (int m = 0; m < 4; ++m)
    #pragma unroll
    for (int n = 0; n < 4; ++n) acc[m][n] = (f32x4){0.f, 0.f, 0.f, 0.f};

  const int ra = tid >> 2;             // 0..63 : A tile row this thread stages
  const int kb = (tid & 3) << 4;       // 0,16,32,48 : k offset (floats)
  const int lc0 = kb >> 3;             // logical chunk of first 8 staged bf16
  const int gr = min(row0 + ra, M_NODES - 1);
  const float* Arow = A + (size_t)gr * K_IN;
  // B base: n = wave*64 + nt*16 + l16 (nt via +8192 elems), k = quad*8 + j
  const short* Wb = Wt + (size_t)(wave * 64 + l16) * K_IN + quad * 8;

  // ---- prologue: stage k0=0 into buf 0
  {
    float4 a0 = *(const float4*)&Arow[kb];
    float4 a1 = *(const float4*)&Arow[kb + 4];
    float4 a2 = *(const float4*)&Arow[kb + 8];
    float4 a3 = *(const float4*)&Arow[kb + 12];
    union { unsigned short s[16]; int4 v[2]; } u;
    u.s[0]=f2bf_u(a0.x); u.s[1]=f2bf_u(a0.y); u.s[2]=f2bf_u(a0.z); u.s[3]=f2bf_u(a0.w);
    u.s[4]=f2bf_u(a1.x); u.s[5]=f2bf_u(a1.y); u.s[6]=f2bf_u(a1.z); u.s[7]=f2bf_u(a1.w);
    u.s[8]=f2bf_u(a2.x); u.s[9]=f2bf_u(a2.y); u.s[10]=f2bf_u(a2.z); u.s[11]=f2bf_u(a2.w);
    u.s[12]=f2bf_u(a3.x); u.s[13]=f2bf_u(a3.y); u.s[14]=f2bf_u(a3.z); u.s[15]=f2bf_u(a3.w);
    #pragma unroll
    for (int c = 0; c < 2; ++c) {
      int phys = (lc0 + c) ^ (ra & 7);
      *(int4*)&As[0][ra * 64 + phys * 8] = u.v[c];
    }
  }
  __syncthreads();

  int cur = 0;
  for (int k0 = 0; k0 < K_IN; k0 += 64) {
    // ---- prefetch next A chunk into registers (hidden under compute)
    float4 p0, p1, p2, p3;
    const bool more = (k0 + 64) < K_IN;
    if (more) {
      p0 = *(const float4*)&Arow[k0 + 64 + kb];
      p1 = *(const float4*)&Arow[k0 + 64 + kb + 4];
      p2 = *(const float4*)&Arow[k0 + 64 + kb + 8];
      p3 = *(const float4*)&Arow[k0 + 64 + kb + 12];
    }
    // ---- compute current buffer: A frags from LDS, B frags from L2
    #pragma unroll
    for (int kh = 0; kh < 2; ++kh) {
      bf16x8 af[4];
      #pragma unroll
      for (int m = 0; m < 4; ++m) {
        int r = m * 16 + l16;
        int phys = (kh * 4 + quad) ^ (l16 & 7);
        af[m] = *(const bf16x8*)&As[cur][r * 64 + phys * 8];
      }
      #pragma unroll
      for (int nt = 0; nt < 4; ++nt) {
        bf16x8 bfr = *(const bf16x8*)(Wb + (size_t)nt * 16 * K_IN + k0 + kh * 32);
        #pragma unroll
        for (int m = 0; m < 4; ++m)
          acc[m][nt] = __builtin_amdgcn_mfma_f32_16x16x32_bf16(af[m], bfr, acc[m][nt], 0, 0, 0);
      }
    }
    // ---- convert + write next chunk to the other buffer (no barrier needed
    // before: its previous readers finished before the last barrier)
    if (more) {
      union { unsigned short s[16]; int4 v[2]; } u;
      u.s[0]=f2bf_u(p0.x); u.s[1]=f2bf_u(p0.y); u.s[2]=f2bf_u(p0.z); u.s[3]=f2bf_u(p0.w);
      u.s[4]=f2bf_u(p1.x); u.s[5]=f2bf_u(p1.y); u.s[6]=f2bf_u(p1.z); u.s[7]=f2bf_u(p1.w);
      u.s[8]=f2bf_u(p2.x); u.s[9]=f2bf_u(p2.y); u.s[10]=f2bf_u(p2.z); u.s[11]=f2bf_u(p2.w);
      u.s[12]=f2bf_u(p3.x); u.s[13]=f2bf_u(p3.y); u.s[14]=f2bf_u(p3.z); u.s[15]=f2bf_u(p3.w);
      #pragma unroll
      for (int c = 0; c < 2; ++c) {
        int phys = (lc0 + c) ^ (ra & 7);
        *(int4*)&As[cur ^ 1][ra * 64 + phys * 8] = u.v[c];
      }
    }
    __syncthreads();
    cur ^= 1;
  }

  // ---- epilogue: C/D row = m*16+quad*4+rr, col = wave*64+nt*16+l16
  #pragma unroll
  for (int m = 0; m < 4; ++m) {
    #pragma unroll
    for (int rr = 0; rr < 4; ++rr) {
      int row = row0 + m * 16 + quad * 4 + rr;
      if (row < M_NODES) {
        #pragma unroll
        for (int nt = 0; nt < 4; ++nt) {
          H[(size_t)row * N_OUT + wave * 64 + nt * 16 + l16] =
              f2bf_u(fast_tanh(acc[m][nt][rr]));
        }
      }
    }
  }
}

// y[i,:] = sum_e vals[e]*x[col[e],:], x bf16 [M,256]. One wave/row; lane holds
// 4 features (8B/edge/lane -> full 512B row per edge, coalesced).
// Edge metadata (col/vals) is loaded ONCE per 64-edge chunk as a per-lane
// vector load, then broadcast via __shfl -> the x-row gathers have no
// load->load dependency and are issued 8-deep (MLP=8 per wave).
__global__ __launch_bounds__(256) void spmm_bf_bf(
    const int* __restrict__ rp, const int* __restrict__ colv,
    const float* __restrict__ vals, const unsigned short* __restrict__ x,
    unsigned short* __restrict__ y) {
  int w = (blockIdx.x * 256 + threadIdx.x) >> 6;
  int lane = threadIdx.x & 63;
  int i = __builtin_amdgcn_readfirstlane(w);
  int s = rp[i], e = rp[i + 1];
  float a0 = 0.f, a1 = 0.f, a2 = 0.f, a3 = 0.f;
  const unsigned short* xl = x + lane * 4;
  for (int base = s; base < e; base += 64) {
    int nn = min(e - base, 64);
    int tl = min(base + lane, e - 1);          // clamped: lanes >= nn unused
    int c_l = colv[tl];
    float v_l = vals[tl];
    int tt = 0;
    for (; tt + 8 <= nn; tt += 8) {
      ushort4 xv[8]; float vv[8];
      #pragma unroll
      for (int j = 0; j < 8; ++j) {
        int c = __shfl(c_l, tt + j);
        vv[j] = __shfl(v_l, tt + j);
        xv[j] = *(const ushort4*)(xl + (size_t)c * N_OUT);
      }
      #pragma unroll
      for (int j = 0; j < 8; ++j) {
        a0 += vv[j] * bfu2f(xv[j].x); a1 += vv[j] * bfu2f(xv[j].y);
        a2 += vv[j] * bfu2f(xv[j].z); a3 += vv[j] * bfu2f(xv[j].w);
      }
    }
    for (; tt + 4 <= nn; tt += 4) {
      ushort4 xv[4]; float vv[4];
      #pragma unroll
      for (int j = 0; j < 4; ++j) {
        int c = __shfl(c_l, tt + j);
        vv[j] = __shfl(v_l, tt + j);
        xv[j] = *(const ushort4*)(xl + (size_t)c * N_OUT);
      }
      #pragma unroll
      for (int j = 0; j < 4; ++j) {
        a0 += vv[j] * bfu2f(xv[j].x); a1 += vv[j] * bfu2f(xv[j].y);
        a2 += vv[j] * bfu2f(xv[j].z); a3 += vv[j] * bfu2f(xv[j].w);
      }
    }
    for (; tt < nn; ++tt) {
      int c = __shfl(c_l, tt);
      float v = __shfl(v_l, tt);
      ushort4 xv = *(const ushort4*)(xl + (size_t)c * N_OUT);
      a0 += v * bfu2f(xv.x); a1 += v * bfu2f(xv.y);
      a2 += v * bfu2f(xv.z); a3 += v * bfu2f(xv.w);
    }
  }
  ushort4 o;
  o.x = f2bf_u(a0); o.y = f2bf_u(a1); o.z = f2bf_u(a2); o.w = f2bf_u(a3);
  *(ushort4*)(y + (size_t)i * N_OUT + lane * 4) = o;
}

// same but f32 output (final layer writes d_out)
__global__ __launch_bounds__(256) void spmm_bf_f32(
    const int* __restrict__ rp, const int* __restrict__ colv,
    const float* __restrict__ vals, const unsigned short* __restrict__ x,
    float* __restrict__ y) {
  int w = (blockIdx.x * 256 + threadIdx.x) >> 6;
  int lane = threadIdx.x & 63;
  int i = __builtin_amdgcn_readfirstlane(w);
  int s = rp[i], e = rp[i + 1];
  float a0 = 0.f, a1 = 0.f, a2 = 0.f, a3 = 0.f;
  const unsigned short* xl = x + lane * 4;
  for (int base = s; base < e; base += 64) {
    int nn = min(e - base, 64);
    int tl = min(base + lane, e - 1);
    int c_l = colv[tl];
    float v_l = vals[tl];
    int tt = 0;
    for (; tt + 8 <= nn; tt += 8) {
      ushort4 xv[8]; float vv[8];
      #pragma unroll
      for (int j = 0; j < 8; ++j) {
        int c = __shfl(c_l, tt + j);
        vv[j] = __shfl(v_l, tt + j);
        xv[j] = *(const ushort4*)(xl + (size_t)c * N_OUT);
      }
      #pragma unroll
      for (int j = 0; j < 8; ++j) {
        a0 += vv[j] * bfu2f(xv[j].x); a1 += vv[j] * bfu2f(xv[j].y);
        a2 += vv[j] * bfu2f(xv[j].z); a3 += vv[j] * bfu2f(xv[j].w);
      }
    }
    for (; tt + 4 <= nn; tt += 4) {
      ushort4 xv[4]; float vv[4];
      #pragma unroll
      for (int j = 0; j < 4; ++j) {
        int c = __shfl(c_l, tt + j);
        vv[j] = __shfl(v_l, tt + j);
        xv[j] = *(const ushort4*)(xl + (size_t)c * N_OUT);
      }
      #pragma unroll
      for (int j = 0; j < 4; ++j) {
        a0 += vv[j] * bfu2f(xv[j].x); a1 += vv[j] * bfu2f(xv[j].y);
        a2 += vv[j] * bfu2f(xv[j].z); a3 += vv[j] * bfu2f(xv[j].w);
      }
    }
    for (; tt < nn; ++tt) {
      int c = __shfl(c_l, tt);
      float v = __shfl(v_l, tt);
      ushort4 xv = *(const ushort4*)(xl + (size_t)c * N_OUT);
      a0 += v * bfu2f(xv.x); a1 += v * bfu2f(xv.y);
      a2 += v * bfu2f(xv.z); a3 += v * bfu2f(xv.w);
    }
  }
  float4 o = {a0, a1, a2, a3};
  *(float4*)(y + (size_t)i * N_OUT + lane * 4) = o;
}

extern "C" void kernel_launch(void* const* d_in, const int* in_sizes, int n_in,
                              void* d_out, int out_size, void* d_ws, size_t ws_size,
                              hipStream_t stream) {
  const float* features = (const float*)d_in[0];
  const float* weight   = (const float*)d_in[1];
  const int*   row      = (const int*)d_in[2];
  const int*   col      = (const int*)d_in[3];
  const float* vals     = (const float*)d_in[4];
  float* out = (float*)d_out;

  char* ws = (char*)d_ws;
  const size_t HB = (size_t)M_NODES * N_OUT * 2;   // 51,200,000 bf16 H
  const size_t RPB = 400016;                        // 100001 ints padded
  unsigned short* H  = (unsigned short*)ws;
  unsigned short* y1 = (unsigned short*)(ws + HB);
  int*   rp = (int*)(ws + 2 * HB);
  short* Wt = (short*)(ws + 2 * HB + RPB);
  // total need: 2*51.2MB + 400016 + 262144 = 103,062,160 B (fits)

  prep_w_kernel<<<512, 256, 0, stream>>>(weight, Wt);
  build_rp_kernel<<<(M_NODES + 1 + 255) / 256, 256, 0, stream>>>(row, rp);
  gemm_tanh_kernel<<<(M_NODES + 63) / 64, 256, 0, stream>>>(features, Wt, H);
  spmm_bf_bf<<<25000, 256, 0, stream>>>(rp, col, vals, H, y1);
  spmm_bf_f32<<<25000, 256, 0, stream>>>(rp, col, vals, y1, out);
}